// Round 12
// baseline (378.540 us; speedup 1.0000x reference)
//
#include <hip/hip_runtime.h>

#define SEQ 2048
#define HDIM 64
#define NH 16

typedef __bf16 bf16x8 __attribute__((ext_vector_type(8)));
typedef float f32x4 __attribute__((ext_vector_type(4)));
typedef unsigned short u16x8 __attribute__((ext_vector_type(8)));
typedef unsigned short u16x4 __attribute__((ext_vector_type(4)));
typedef _Float16 f16x4 __attribute__((ext_vector_type(4)));
typedef unsigned int u32x2 __attribute__((ext_vector_type(2)));
typedef unsigned long long u64;

__device__ __forceinline__ unsigned short f2bf(float f) {  // RTNE
  unsigned int u = __builtin_bit_cast(unsigned int, f);
  u = (u + 0x7FFFu + ((u >> 16) & 1u)) >> 16;
  return (unsigned short)u;
}

__device__ __forceinline__ bf16x8 cvt8(f32x4 a, f32x4 b) {
  u16x8 u;
  u[0] = f2bf(a[0]); u[1] = f2bf(a[1]); u[2] = f2bf(a[2]); u[3] = f2bf(a[3]);
  u[4] = f2bf(b[0]); u[5] = f2bf(b[1]); u[6] = f2bf(b[2]); u[7] = f2bf(b[3]);
  return __builtin_bit_cast(bf16x8, u);
}

__device__ __forceinline__ f32x4 mfma16(bf16x8 a, bf16x8 b, f32x4 c) {
  return __builtin_amdgcn_mfma_f32_16x16x32_bf16(a, b, c, 0, 0, 0);
}
__device__ __forceinline__ f32x4 mfma16h(f16x4 a, f16x4 b, f32x4 c) {
  return __builtin_amdgcn_mfma_f32_16x16x16f16(a, b, c, 0, 0, 0);
}

// pack 4 f32 -> f16x4 via v_cvt_pkrtz (RTZ — round-1 proven numerics)
__device__ __forceinline__ f16x4 pk4h(float a, float b, float cc, float d) {
  auto h0 = __builtin_amdgcn_cvt_pkrtz(a, b);
  auto h1 = __builtin_amdgcn_cvt_pkrtz(cc, d);
  u32x2 u = { __builtin_bit_cast(unsigned int, h0),
              __builtin_bit_cast(unsigned int, h1) };
  return __builtin_bit_cast(f16x4, u);
}

// log2(e)/32: folds 1/sqrt(EMBED_DIM) and exp->exp2 into the q-projection.
#define QSCALE 0.045084220027780106f

// ---------------- Kernel 1: MERGED prologue — one launch, blockIdx ranges:
//   [0,1536)      qkv projection (3 x 512 blocks; MFMA-heavy, starts first)
//   [1536,2560)   Wo fp32->bf16 (1024 blocks)
//   [2560,6656)   mask int32 -> bitmask (4096 blocks; BW-bound, overlaps qkv)
// Per-block code and data byte-identical to the previous separate kernels —
// outputs bit-identical; only launch scheduling changes (removes 2 launch
// boundaries, lets BW-bound maskpack fill memory idle under qkv's MFMA).
__global__ __launch_bounds__(256) void prep(
    const float* __restrict__ keys, const float* __restrict__ values,
    const float* __restrict__ queries,
    const float* __restrict__ Wk, const float* __restrict__ Wv,
    const float* __restrict__ Wq, const float* __restrict__ Wo,
    const int* __restrict__ mask,
    unsigned short* __restrict__ kb, unsigned short* __restrict__ vb,
    unsigned short* __restrict__ qb, unsigned short* __restrict__ wob,
    u64* __restrict__ bits)
{
  const int bid = blockIdx.x;
  const int tid = threadIdx.x;

  if (bid >= 2560) {            // ---- maskpack role ----
    const int mbx = bid - 2560;
    const int wid = mbx * 4 + (tid >> 6);
    const int lane = tid & 63;
    const int* src = mask + (size_t)wid * 1024 + lane;
    u64* dst = bits + (size_t)wid * 16;
    #pragma unroll
    for (int i = 0; i < 16; ++i) {
      u64 b = __ballot(src[i * 64] != 0);
      if (lane == 0) dst[i] = b;
    }
    return;
  }

  if (bid >= 1536) {            // ---- cvt_wo role ----
    const int cbx = bid - 1536;
    int i = (cbx * 256 + tid) * 4;
    f32x4 v = *reinterpret_cast<const f32x4*>(Wo + i);
    u16x4 o;
    o[0] = f2bf(v[0]); o[1] = f2bf(v[1]); o[2] = f2bf(v[2]); o[3] = f2bf(v[3]);
    *reinterpret_cast<u16x4*>(wob + i) = o;
    return;
  }

  // ---- qkv_proj role: Y^T = W.X^T; K,Q out bf16 [m][d]; V out f16 V^T ----
  const int which = bid >> 9;            // 0..2 (512 blocks each)
  const int bx = bid & 511;
  const float* __restrict__ in = (which == 0) ? keys : (which == 1) ? values : queries;
  const float* __restrict__ W  = (which == 0) ? Wk   : (which == 1) ? Wv     : Wq;
  unsigned short* __restrict__ op = (which == 0) ? kb : (which == 1) ? vb : qb;
  const float osc = (which == 2) ? QSCALE : 1.0f;
  const bool asf16 = (which == 1);

  const int w = tid >> 6, lane = tid & 63, c = lane & 15, quad = lane >> 4;

  // A-frags of W: lane holds W[dt*16 + c][hh*32 + quad*8 ..+7]
  bf16x8 aw[4][2];
  #pragma unroll
  for (int dt = 0; dt < 4; ++dt)
    #pragma unroll
    for (int hh = 0; hh < 2; ++hh) {
      const float* wr = W + (dt * 16 + c) * 64 + hh * 32 + quad * 8;
      aw[dt][hh] = cvt8(*(const f32x4*)wr, *(const f32x4*)(wr + 4));
    }

  const int m00 = bx * 256 + w * 64;
  #pragma unroll
  for (int s = 0; s < 4; ++s) {
    const int m0 = m00 + s * 16;
    const float* xr = in + (size_t)(m0 + c) * 64;
    bf16x8 x0 = cvt8(*(const f32x4*)(xr + quad * 8), *(const f32x4*)(xr + quad * 8 + 4));
    bf16x8 x1 = cvt8(*(const f32x4*)(xr + 32 + quad * 8), *(const f32x4*)(xr + 36 + quad * 8));
    f32x4 acc[4] = {};
    #pragma unroll
    for (int dt = 0; dt < 4; ++dt) {
      acc[dt] = mfma16(aw[dt][0], x0, acc[dt]);
      acc[dt] = mfma16(aw[dt][1], x1, acc[dt]);
    }
    if (asf16) {
      // V^T: element (d, s_local) -> vb[head*64*SEQ + d*SEQ + s_local]
      unsigned short* vt = op + (size_t)(m0 >> 11) * (64 * SEQ)
                              + ((m0 & 2047) + c);
      #pragma unroll
      for (int dt = 0; dt < 4; ++dt) {
        u16x4 pk = __builtin_bit_cast(u16x4,
            pk4h(acc[dt][0], acc[dt][1], acc[dt][2], acc[dt][3]));
        #pragma unroll
        for (int r = 0; r < 4; ++r)
          vt[(size_t)(dt * 16 + quad * 4 + r) * SEQ] = pk[r];
      }
    } else {
      // D[d = dt*16 + quad*4 + r][m = c] -> 4 consecutive d per lane: u16x4
      unsigned short* orow = op + (size_t)(m0 + c) * 64 + quad * 4;
      #pragma unroll
      for (int dt = 0; dt < 4; ++dt) {
        u16x4 pk;
        pk[0] = f2bf(acc[dt][0] * osc); pk[1] = f2bf(acc[dt][1] * osc);
        pk[2] = f2bf(acc[dt][2] * osc); pk[3] = f2bf(acc[dt][3] * osc);
        *(u16x4*)(orow + dt * 16) = pk;
      }
    }
  }
}

// ---------------- Kernel 2: attention (round-10/11 measured best: ~119us).
// q-tile 128 / 1024 blocks, single-buffer LDS, split K/V staging, XCD
// swizzle, raw v_exp_f32, mask prefetch, s_setprio around PV MFMA cluster.
__global__ __launch_bounds__(256, 4) void attn4(
    const unsigned short* __restrict__ qb, const unsigned short* __restrict__ kb,
    const unsigned short* __restrict__ vb, const u64* __restrict__ mbits,
    unsigned short* __restrict__ att)
{
  __shared__ __attribute__((aligned(16))) unsigned short Kl[64][72]; // bf16 [key][d]
  __shared__ __attribute__((aligned(16))) unsigned short Vt[64][72]; // f16  [d][key]
  __shared__ unsigned int mlut[16][2];

  const int tid = threadIdx.x;
  const int w = tid >> 6, lane = tid & 63, c = lane & 15, quad = lane >> 4;

  // bid = (G&7) + 8*(qx + 16*(G>>3)): bid%8 == G%8 -> same head-group, same XCD
  const int bid = blockIdx.x;
  const int xcd = bid & 7, rr = bid >> 3;
  const int qx = rr & 15, gh = rr >> 4;
  const int G = xcd + gh * 8;            // head-group = n*NH + h, 0..63
  const int n = G >> 4;
  const int q0 = qx * 128;
  const size_t hb = (size_t)G * (SEQ * HDIM);

  if (tid < 16) {
    unsigned m = tid;
    mlut[m][0] = ((m & 1u) ? 0xFFFFu : 0u) | ((m & 2u) ? 0xFFFF0000u : 0u);
    mlut[m][1] = ((m & 4u) ? 0xFFFFu : 0u) | ((m & 8u) ? 0xFFFF0000u : 0u);
  }

  bf16x8 aq[2][2];
  #pragma unroll
  for (int qt = 0; qt < 2; ++qt) {
    const unsigned short* qr = qb + hb + (size_t)(q0 + qt * 64 + w * 16 + c) * HDIM;
    aq[qt][0] = *reinterpret_cast<const bf16x8*>(qr + quad * 8);
    aq[qt][1] = *reinterpret_cast<const bf16x8*>(qr + 32 + quad * 8);
  }

  f32x4 o[2][4] = {};    // O^T: lane q=qbase+c; d = dt*16 + quad*4 + r
  f32x4 osum[2] = {};    // MFMA-accumulated row sums (all entries identical)
  const f16x4 ones = {(_Float16)1.f, (_Float16)1.f, (_Float16)1.f, (_Float16)1.f};

  const u64* mb = mbits + ((size_t)n * SEQ + q0 + w * 16 + c) * 32;

  // Staging: waves 0-1 copy K rows [key][d]; waves 2-3 copy V^T rows [d][key].
  const bool isK = tid < 128;
  const int srow = (tid & 127) >> 1, scol = (tid & 1) * 32;
  const unsigned short* sptr = (isK ? kb : vb) + hb
      + (size_t)srow * (isK ? HDIM : SEQ) + scol;
  const int sadv = isK ? 64 * HDIM : 64;   // elements advanced per step
  unsigned short (*Sl)[72] = isK ? Kl : Vt;

  // prologue: prefetch tile 0 + mask words 0 into registers
  u16x8 st0 = *(const u16x8*)(sptr);
  u16x8 st1 = *(const u16x8*)(sptr + 8);
  u16x8 st2 = *(const u16x8*)(sptr + 16);
  u16x8 st3 = *(const u16x8*)(sptr + 24);
  u64 mcur0 = mb[0];
  u64 mcur1 = mb[2048];

  for (int step = 0; step < 32; ++step) {
    __syncthreads();   // previous step's LDS reads complete
    *(u16x8*)&Sl[srow][scol]      = st0;
    *(u16x8*)&Sl[srow][scol + 8]  = st1;
    *(u16x8*)&Sl[srow][scol + 16] = st2;
    *(u16x8*)&Sl[srow][scol + 24] = st3;
    u64 b0 = mcur0 >> (quad * 4);
    u64 b1 = mcur1 >> (quad * 4);
    if (step < 31) {   // prefetch next tile + next mask words
      const unsigned short* p = sptr + (size_t)(step + 1) * sadv;
      st0 = *(const u16x8*)(p);
      st1 = *(const u16x8*)(p + 8);
      st2 = *(const u16x8*)(p + 16);
      st3 = *(const u16x8*)(p + 24);
      mcur0 = mb[step + 1];
      mcur1 = mb[2048 + step + 1];
    }
    __syncthreads();

    // E^T = K.Q^T : per key-tile t, K A-frag shared by both q-tiles
    f32x4 e[2][4] = {};
    #pragma unroll
    for (int t = 0; t < 4; ++t) {
      bf16x8 kf0 = *reinterpret_cast<const bf16x8*>(&Kl[t * 16 + c][quad * 8]);
      bf16x8 kf1 = *reinterpret_cast<const bf16x8*>(&Kl[t * 16 + c][32 + quad * 8]);
      #pragma unroll
      for (int qt = 0; qt < 2; ++qt) {
        e[qt][t] = mfma16(kf0, aq[qt][0], e[qt][t]);
        e[qt][t] = mfma16(kf1, aq[qt][1], e[qt][t]);
      }
    }

    // exp2 (raw v_exp_f32; in-range so bit-identical to ocml exp2f)
    // -> pack f16 -> AND with mask-LUT words
    f16x4 pf[2][4];
    #pragma unroll
    for (int qt = 0; qt < 2; ++qt) {
      u64 bb = qt ? b1 : b0;
      unsigned int lo = (unsigned int)bb, hi = (unsigned int)(bb >> 32);
      #pragma unroll
      for (int t = 0; t < 4; ++t) {
        unsigned int nib = (((t & 2) ? hi : lo) >> ((t & 1) * 16)) & 0xFu;
        f32x4 ev = e[qt][t];
        f16x4 pk = pk4h(__builtin_amdgcn_exp2f(ev[0]),
                        __builtin_amdgcn_exp2f(ev[1]),
                        __builtin_amdgcn_exp2f(ev[2]),
                        __builtin_amdgcn_exp2f(ev[3]));
        u32x2 pw = __builtin_bit_cast(u32x2, pk);
        pw[0] &= mlut[nib][0];
        pw[1] &= mlut[nib][1];
        pf[qt][t] = __builtin_bit_cast(f16x4, pw);
      }
    }

    // O^T += V^T.P^T ; row sums via ones-operand MFMA. setprio favors the
    // MFMA-entering wave over co-resident waves still issuing loads (T5).
    __builtin_amdgcn_s_setprio(1);
    #pragma unroll
    for (int dt = 0; dt < 4; ++dt) {
      #pragma unroll
      for (int t = 0; t < 4; ++t) {
        f16x4 vf = __builtin_bit_cast(f16x4,
            *(const u16x4*)&Vt[dt * 16 + c][t * 16 + quad * 4]);
        o[0][dt] = mfma16h(vf, pf[0][t], o[0][dt]);
        o[1][dt] = mfma16h(vf, pf[1][t], o[1][dt]);
      }
    }
    #pragma unroll
    for (int t = 0; t < 4; ++t) {
      osum[0] = mfma16h(ones, pf[0][t], osum[0]);
      osum[1] = mfma16h(ones, pf[1][t], osum[1]);
    }
    __builtin_amdgcn_s_setprio(0);
  }

  #pragma unroll
  for (int qt = 0; qt < 2; ++qt) {
    float inv = 1.0f / osum[qt][0];   // all 4 entries / all quads identical
    unsigned short* orow =
        att + hb + (size_t)(q0 + qt * 64 + w * 16 + c) * HDIM + quad * 4;
    #pragma unroll
    for (int dt = 0; dt < 4; ++dt) {
      u16x4 pk = { f2bf(o[qt][dt][0] * inv), f2bf(o[qt][dt][1] * inv),
                   f2bf(o[qt][dt][2] * inv), f2bf(o[qt][dt][3] * inv) };
      *(u16x4*)(orow + dt * 16) = pk;
    }
  }
}

// ---------------- Kernel 3: output projection, 64x128 tiles, register-
// prefetched staging, pre-converted bf16 Wo (round-5/9 proven version).
__global__ __launch_bounds__(256) void out_proj3(
    const unsigned short* __restrict__ att, const unsigned short* __restrict__ wob,
    const float* __restrict__ bo, float* __restrict__ out)
{
  __shared__ __attribute__((aligned(16))) unsigned short As[64][72];
  __shared__ __attribute__((aligned(16))) unsigned short Bs[128][72];

  const int nb = blockIdx.x, mbk = blockIdx.y;
  const int tid = threadIdx.x;
  const int w = tid >> 6, lane = tid & 63, c = lane & 15, quad = lane >> 4;
  const int wm = w & 1, wn = w >> 1;
  const int m0 = mbk * 64, n0 = nb * 128;
  const int arow = tid >> 2, acol = (tid & 3) * 16;
  const int brow = tid >> 1, bcol = (tid & 1) * 32;

  const unsigned short* sa = att + (size_t)(m0 + arow) * 1024 + acol;
  const unsigned short* sb = wob + (size_t)(n0 + brow) * 1024 + bcol;

  f32x4 acc[2][4] = {};

  // prologue: prefetch k0=0 tiles into registers
  u16x8 ra0 = *(const u16x8*)(sa);
  u16x8 ra1 = *(const u16x8*)(sa + 8);
  u16x8 rb0 = *(const u16x8*)(sb);
  u16x8 rb1 = *(const u16x8*)(sb + 8);
  u16x8 rb2 = *(const u16x8*)(sb + 16);
  u16x8 rb3 = *(const u16x8*)(sb + 24);

  for (int k0 = 0; k0 < 1024; k0 += 64) {
    __syncthreads();   // previous iter's LDS reads complete
    *(u16x8*)&As[arow][acol]          = ra0;
    *(u16x8*)&As[arow][acol + 8]      = ra1;
    *(u16x8*)&Bs[brow][bcol]          = rb0;
    *(u16x8*)&Bs[brow][bcol + 8]      = rb1;
    *(u16x8*)&Bs[brow][bcol + 16]     = rb2;
    *(u16x8*)&Bs[brow][bcol + 24]     = rb3;
    if (k0 < 960) {    // prefetch next K-tile; latency hidden behind MFMAs
      const unsigned short* pa = sa + k0 + 64;
      const unsigned short* pb = sb + k0 + 64;
      ra0 = *(const u16x8*)(pa);
      ra1 = *(const u16x8*)(pa + 8);
      rb0 = *(const u16x8*)(pb);
      rb1 = *(const u16x8*)(pb + 8);
      rb2 = *(const u16x8*)(pb + 16);
      rb3 = *(const u16x8*)(pb + 24);
    }
    __syncthreads();

    #pragma unroll
    for (int kk = 0; kk < 64; kk += 32) {
      bf16x8 af[2];
      #pragma unroll
      for (int mt = 0; mt < 2; ++mt)
        af[mt] = *reinterpret_cast<const bf16x8*>(&As[wm * 32 + mt * 16 + c][kk + quad * 8]);
      #pragma unroll
      for (int nt = 0; nt < 4; ++nt) {
        bf16x8 bf_ = *reinterpret_cast<const bf16x8*>(&Bs[wn * 64 + nt * 16 + c][kk + quad * 8]);
        #pragma unroll
        for (int mt = 0; mt < 2; ++mt)
          acc[mt][nt] = mfma16(af[mt], bf_, acc[mt][nt]);
      }
    }
  }

  #pragma unroll
  for (int nt = 0; nt < 4; ++nt) {
    const int col = n0 + wn * 64 + nt * 16 + c;
    const float bias = bo[col];
    #pragma unroll
    for (int mt = 0; mt < 2; ++mt)
      #pragma unroll
      for (int r = 0; r < 4; ++r)
        out[(size_t)(m0 + wm * 32 + mt * 16 + quad * 4 + r) * 1024 + col] =
            acc[mt][nt][r] + bias;
  }
}

extern "C" void kernel_launch(void* const* d_in, const int* in_sizes, int n_in,
                              void* d_out, int out_size, void* d_ws, size_t ws_size,
                              hipStream_t stream) {
  const float* keys    = (const float*)d_in[0];
  const float* values  = (const float*)d_in[1];
  const float* queries = (const float*)d_in[2];
  const int*   mask    = (const int*)d_in[3];
  const float* Wk      = (const float*)d_in[4];
  const float* Wv      = (const float*)d_in[5];
  const float* Wq      = (const float*)d_in[6];
  const float* Wo      = (const float*)d_in[7];
  const float* bo      = (const float*)d_in[8];
  float* out = (float*)d_out;

  const size_t T = (size_t)4 * NH * SEQ * HDIM;  // 8388608 elements per tensor
  unsigned short* ws  = (unsigned short*)d_ws;
  unsigned short* kb  = ws;
  unsigned short* vb  = kb + T;                  // holds V^T [head][d][seq] f16
  unsigned short* qb  = vb + T;
  unsigned short* att = qb + T;
  unsigned short* wob = att + T;                 // 1024*1024 u16
  u64* mbits = (u64*)(wob + 1024 * 1024);        // 262144 u64 (2 MB)

  prep<<<dim3(6656), 256, 0, stream>>>(keys, values, queries,
                                       Wk, Wv, Wq, Wo, mask,
                                       kb, vb, qb, wob, mbits);
  attn4<<<dim3(1024), 256, 0, stream>>>(qb, kb, vb, mbits, att);
  out_proj3<<<dim3(8, 128), 256, 0, stream>>>(att, wob, bo, out);
}

// Round 14
// 346.742 us; speedup vs baseline: 1.0917x; 1.0917x over previous
//
#include <hip/hip_runtime.h>

#define SEQ 2048
#define HDIM 64
#define NH 16

typedef __bf16 bf16x8 __attribute__((ext_vector_type(8)));
typedef float f32x4 __attribute__((ext_vector_type(4)));
typedef unsigned short u16x8 __attribute__((ext_vector_type(8)));
typedef unsigned short u16x4 __attribute__((ext_vector_type(4)));
typedef _Float16 f16x4 __attribute__((ext_vector_type(4)));
typedef unsigned int u32x2 __attribute__((ext_vector_type(2)));
typedef unsigned long long u64;

__device__ __forceinline__ unsigned short f2bf(float f) {  // RTNE
  unsigned int u = __builtin_bit_cast(unsigned int, f);
  u = (u + 0x7FFFu + ((u >> 16) & 1u)) >> 16;
  return (unsigned short)u;
}

__device__ __forceinline__ bf16x8 cvt8(f32x4 a, f32x4 b) {
  u16x8 u;
  u[0] = f2bf(a[0]); u[1] = f2bf(a[1]); u[2] = f2bf(a[2]); u[3] = f2bf(a[3]);
  u[4] = f2bf(b[0]); u[5] = f2bf(b[1]); u[6] = f2bf(b[2]); u[7] = f2bf(b[3]);
  return __builtin_bit_cast(bf16x8, u);
}

__device__ __forceinline__ f32x4 mfma16(bf16x8 a, bf16x8 b, f32x4 c) {
  return __builtin_amdgcn_mfma_f32_16x16x32_bf16(a, b, c, 0, 0, 0);
}
__device__ __forceinline__ f32x4 mfma16h(f16x4 a, f16x4 b, f32x4 c) {
  return __builtin_amdgcn_mfma_f32_16x16x16f16(a, b, c, 0, 0, 0);
}

// pack 4 f32 -> f16x4 via v_cvt_pkrtz (RTZ — round-1 proven numerics)
__device__ __forceinline__ f16x4 pk4h(float a, float b, float cc, float d) {
  auto h0 = __builtin_amdgcn_cvt_pkrtz(a, b);
  auto h1 = __builtin_amdgcn_cvt_pkrtz(cc, d);
  u32x2 u = { __builtin_bit_cast(unsigned int, h0),
              __builtin_bit_cast(unsigned int, h1) };
  return __builtin_bit_cast(f16x4, u);
}

// log2(e)/32: folds 1/sqrt(EMBED_DIM) and exp->exp2 into the q-projection.
#define QSCALE 0.045084220027780106f

// ---------------- Kernel 1: QKV projection. K,Q out bf16 [m][d]; V out f16
// TILED V^T: [head][seq/64][d][64]. Each wave owns one 64-seq chunk, so the
// transpose happens in a PRIVATE 64x72 LDS tile (no barrier) and the global
// store is 8 fully-contiguous 1KB wave-stores — replaces the 64 scalar
// scattered stores/thread that made the prologue store-latency-bound
// (round 12: prep at 1.3 TB/s with all pipes <16% busy).
__global__ __launch_bounds__(256) void qkv_proj(
    const float* __restrict__ keys, const float* __restrict__ values,
    const float* __restrict__ queries,
    const float* __restrict__ Wk, const float* __restrict__ Wv,
    const float* __restrict__ Wq,
    unsigned short* __restrict__ kb, unsigned short* __restrict__ vb,
    unsigned short* __restrict__ qb)
{
  __shared__ __attribute__((aligned(16))) unsigned short vt[4][64][72];

  const int which = blockIdx.y;
  const float* __restrict__ in = (which == 0) ? keys : (which == 1) ? values : queries;
  const float* __restrict__ W  = (which == 0) ? Wk   : (which == 1) ? Wv     : Wq;
  unsigned short* __restrict__ op = (which == 0) ? kb : (which == 1) ? vb : qb;
  const float osc = (which == 2) ? QSCALE : 1.0f;
  const bool asf16 = (which == 1);

  const int tid = threadIdx.x;
  const int w = tid >> 6, lane = tid & 63, c = lane & 15, quad = lane >> 4;

  // A-frags of W: lane holds W[dt*16 + c][hh*32 + quad*8 ..+7]
  bf16x8 aw[4][2];
  #pragma unroll
  for (int dt = 0; dt < 4; ++dt)
    #pragma unroll
    for (int hh = 0; hh < 2; ++hh) {
      const float* wr = W + (dt * 16 + c) * 64 + hh * 32 + quad * 8;
      aw[dt][hh] = cvt8(*(const f32x4*)wr, *(const f32x4*)(wr + 4));
    }

  const int m00 = blockIdx.x * 256 + w * 64;
  #pragma unroll
  for (int s = 0; s < 4; ++s) {
    const int m0 = m00 + s * 16;
    const float* xr = in + (size_t)(m0 + c) * 64;
    bf16x8 x0 = cvt8(*(const f32x4*)(xr + quad * 8), *(const f32x4*)(xr + quad * 8 + 4));
    bf16x8 x1 = cvt8(*(const f32x4*)(xr + 32 + quad * 8), *(const f32x4*)(xr + 36 + quad * 8));
    f32x4 acc[4] = {};
    #pragma unroll
    for (int dt = 0; dt < 4; ++dt) {
      acc[dt] = mfma16(aw[dt][0], x0, acc[dt]);
      acc[dt] = mfma16(aw[dt][1], x1, acc[dt]);
    }
    if (asf16) {
      // stage into per-wave LDS transpose tile [d][seq_local]
      #pragma unroll
      for (int dt = 0; dt < 4; ++dt) {
        u16x4 pk = __builtin_bit_cast(u16x4,
            pk4h(acc[dt][0], acc[dt][1], acc[dt][2], acc[dt][3]));
        #pragma unroll
        for (int r = 0; r < 4; ++r)
          vt[w][dt * 16 + quad * 4 + r][s * 16 + c] = pk[r];
      }
    } else {
      // D[d = dt*16 + quad*4 + r][m = c] -> 4 consecutive d per lane: u16x4
      unsigned short* orow = op + (size_t)(m0 + c) * 64 + quad * 4;
      #pragma unroll
      for (int dt = 0; dt < 4; ++dt) {
        u16x4 pk;
        pk[0] = f2bf(acc[dt][0] * osc); pk[1] = f2bf(acc[dt][1] * osc);
        pk[2] = f2bf(acc[dt][2] * osc); pk[3] = f2bf(acc[dt][3] * osc);
        *(u16x4*)(orow + dt * 16) = pk;
      }
    }
  }

  if (asf16) {
    // flush the wave's 64x64 tile: 8 instrs x contiguous 1KB wave-stores.
    // tile base: head = m00>>11, chunk = (m00&2047)>>6 (wave-aligned).
    unsigned short* tb = op + (size_t)(m00 >> 11) * (64 * SEQ)
                            + (size_t)((m00 & 2047) >> 6) * (64 * 64);
    #pragma unroll
    for (int k = 0; k < 8; ++k) {
      const int row = k * 8 + (lane >> 3), colb = (lane & 7) * 8;
      u16x8 v = *(const u16x8*)&vt[w][row][colb];
      *(u16x8*)(tb + (size_t)row * 64 + colb) = v;
    }
  }
}

// ---------------- Kernel 2: Wo fp32 -> bf16 (one-time 4MB; keeps out_proj3
// B-panel re-reads at bf16 width — in-proj fusion regressed in round 10).
__global__ __launch_bounds__(256) void cvt_wo(const float* __restrict__ src,
                                              unsigned short* __restrict__ dst)
{
  int i = (blockIdx.x * 256 + threadIdx.x) * 4;
  f32x4 v = *reinterpret_cast<const f32x4*>(src + i);
  u16x4 o;
  o[0] = f2bf(v[0]); o[1] = f2bf(v[1]); o[2] = f2bf(v[2]); o[3] = f2bf(v[3]);
  *reinterpret_cast<u16x4*>(dst + i) = o;
}

// ---------------- Kernel 3: pack mask int32 -> bitmask (67MB -> 2MB) ------
__global__ __launch_bounds__(256) void maskpack(const int* __restrict__ mask,
                                                u64* __restrict__ bits)
{
  const int wid = blockIdx.x * 4 + (threadIdx.x >> 6);
  const int lane = threadIdx.x & 63;
  const int* src = mask + (size_t)wid * 1024 + lane;
  u64* dst = bits + (size_t)wid * 16;
  #pragma unroll
  for (int i = 0; i < 16; ++i) {
    u64 b = __ballot(src[i * 64] != 0);
    if (lane == 0) dst[i] = b;
  }
}

// ---------------- Kernel 4: attention (round-10/11 measured best ~119us).
// Tiled V^T makes the V staging address formula IDENTICAL to K's:
// both read (base + hb + srow*64 + scol), advancing 4096 per step.
__global__ __launch_bounds__(256, 4) void attn4(
    const unsigned short* __restrict__ qb, const unsigned short* __restrict__ kb,
    const unsigned short* __restrict__ vb, const u64* __restrict__ mbits,
    unsigned short* __restrict__ att)
{
  __shared__ __attribute__((aligned(16))) unsigned short Kl[64][72]; // bf16 [key][d]
  __shared__ __attribute__((aligned(16))) unsigned short Vt[64][72]; // f16  [d][key]
  __shared__ unsigned int mlut[16][2];

  const int tid = threadIdx.x;
  const int w = tid >> 6, lane = tid & 63, c = lane & 15, quad = lane >> 4;

  // bid = (G&7) + 8*(qx + 16*(G>>3)): bid%8 == G%8 -> same head-group, same XCD
  const int bid = blockIdx.x;
  const int xcd = bid & 7, rr = bid >> 3;
  const int qx = rr & 15, gh = rr >> 4;
  const int G = xcd + gh * 8;            // head-group = n*NH + h, 0..63
  const int n = G >> 4;
  const int q0 = qx * 128;
  const size_t hb = (size_t)G * (SEQ * HDIM);

  if (tid < 16) {
    unsigned m = tid;
    mlut[m][0] = ((m & 1u) ? 0xFFFFu : 0u) | ((m & 2u) ? 0xFFFF0000u : 0u);
    mlut[m][1] = ((m & 4u) ? 0xFFFFu : 0u) | ((m & 8u) ? 0xFFFF0000u : 0u);
  }

  bf16x8 aq[2][2];
  #pragma unroll
  for (int qt = 0; qt < 2; ++qt) {
    const unsigned short* qr = qb + hb + (size_t)(q0 + qt * 64 + w * 16 + c) * HDIM;
    aq[qt][0] = *reinterpret_cast<const bf16x8*>(qr + quad * 8);
    aq[qt][1] = *reinterpret_cast<const bf16x8*>(qr + 32 + quad * 8);
  }

  f32x4 o[2][4] = {};    // O^T: lane q=qbase+c; d = dt*16 + quad*4 + r
  f32x4 osum[2] = {};    // MFMA-accumulated row sums (all entries identical)
  const f16x4 ones = {(_Float16)1.f, (_Float16)1.f, (_Float16)1.f, (_Float16)1.f};

  const u64* mb = mbits + ((size_t)n * SEQ + q0 + w * 16 + c) * 32;

  // Staging: waves 0-1 copy K rows [key][d]; waves 2-3 copy V^T tile rows.
  // Unified addressing: row srow of a 64x64-u16 tile, tiles 4096 apart.
  const bool isK = tid < 128;
  const int srow = (tid & 127) >> 1, scol = (tid & 1) * 32;
  const unsigned short* sptr = (isK ? kb : vb) + hb + (size_t)srow * 64 + scol;
  unsigned short (*Sl)[72] = isK ? Kl : Vt;

  // prologue: prefetch tile 0 + mask words 0 into registers
  u16x8 st0 = *(const u16x8*)(sptr);
  u16x8 st1 = *(const u16x8*)(sptr + 8);
  u16x8 st2 = *(const u16x8*)(sptr + 16);
  u16x8 st3 = *(const u16x8*)(sptr + 24);
  u64 mcur0 = mb[0];
  u64 mcur1 = mb[2048];

  for (int step = 0; step < 32; ++step) {
    __syncthreads();   // previous step's LDS reads complete
    *(u16x8*)&Sl[srow][scol]      = st0;
    *(u16x8*)&Sl[srow][scol + 8]  = st1;
    *(u16x8*)&Sl[srow][scol + 16] = st2;
    *(u16x8*)&Sl[srow][scol + 24] = st3;
    u64 b0 = mcur0 >> (quad * 4);
    u64 b1 = mcur1 >> (quad * 4);
    if (step < 31) {   // prefetch next tile + next mask words
      const unsigned short* p = sptr + (size_t)(step + 1) * 4096;
      st0 = *(const u16x8*)(p);
      st1 = *(const u16x8*)(p + 8);
      st2 = *(const u16x8*)(p + 16);
      st3 = *(const u16x8*)(p + 24);
      mcur0 = mb[step + 1];
      mcur1 = mb[2048 + step + 1];
    }
    __syncthreads();

    // E^T = K.Q^T : per key-tile t, K A-frag shared by both q-tiles
    f32x4 e[2][4] = {};
    #pragma unroll
    for (int t = 0; t < 4; ++t) {
      bf16x8 kf0 = *reinterpret_cast<const bf16x8*>(&Kl[t * 16 + c][quad * 8]);
      bf16x8 kf1 = *reinterpret_cast<const bf16x8*>(&Kl[t * 16 + c][32 + quad * 8]);
      #pragma unroll
      for (int qt = 0; qt < 2; ++qt) {
        e[qt][t] = mfma16(kf0, aq[qt][0], e[qt][t]);
        e[qt][t] = mfma16(kf1, aq[qt][1], e[qt][t]);
      }
    }

    // exp2 (raw v_exp_f32; in-range so bit-identical to ocml exp2f)
    // -> pack f16 -> AND with mask-LUT words
    f16x4 pf[2][4];
    #pragma unroll
    for (int qt = 0; qt < 2; ++qt) {
      u64 bb = qt ? b1 : b0;
      unsigned int lo = (unsigned int)bb, hi = (unsigned int)(bb >> 32);
      #pragma unroll
      for (int t = 0; t < 4; ++t) {
        unsigned int nib = (((t & 2) ? hi : lo) >> ((t & 1) * 16)) & 0xFu;
        f32x4 ev = e[qt][t];
        f16x4 pk = pk4h(__builtin_amdgcn_exp2f(ev[0]),
                        __builtin_amdgcn_exp2f(ev[1]),
                        __builtin_amdgcn_exp2f(ev[2]),
                        __builtin_amdgcn_exp2f(ev[3]));
        u32x2 pw = __builtin_bit_cast(u32x2, pk);
        pw[0] &= mlut[nib][0];
        pw[1] &= mlut[nib][1];
        pf[qt][t] = __builtin_bit_cast(f16x4, pw);
      }
    }

    // O^T += V^T.P^T ; row sums via ones-operand MFMA. setprio favors the
    // MFMA-entering wave over co-resident waves still issuing loads (T5).
    __builtin_amdgcn_s_setprio(1);
    #pragma unroll
    for (int dt = 0; dt < 4; ++dt) {
      #pragma unroll
      for (int t = 0; t < 4; ++t) {
        f16x4 vf = __builtin_bit_cast(f16x4,
            *(const u16x4*)&Vt[dt * 16 + c][t * 16 + quad * 4]);
        o[0][dt] = mfma16h(vf, pf[0][t], o[0][dt]);
        o[1][dt] = mfma16h(vf, pf[1][t], o[1][dt]);
      }
    }
    #pragma unroll
    for (int t = 0; t < 4; ++t) {
      osum[0] = mfma16h(ones, pf[0][t], osum[0]);
      osum[1] = mfma16h(ones, pf[1][t], osum[1]);
    }
    __builtin_amdgcn_s_setprio(0);
  }

  #pragma unroll
  for (int qt = 0; qt < 2; ++qt) {
    float inv = 1.0f / osum[qt][0];   // all 4 entries / all quads identical
    unsigned short* orow =
        att + hb + (size_t)(q0 + qt * 64 + w * 16 + c) * HDIM + quad * 4;
    #pragma unroll
    for (int dt = 0; dt < 4; ++dt) {
      u16x4 pk = { f2bf(o[qt][dt][0] * inv), f2bf(o[qt][dt][1] * inv),
                   f2bf(o[qt][dt][2] * inv), f2bf(o[qt][dt][3] * inv) };
      *(u16x4*)(orow + dt * 16) = pk;
    }
  }
}

// ---------------- Kernel 5: output projection, 64x128 tiles, register-
// prefetched staging, pre-converted bf16 Wo (round-5/9 proven version).
__global__ __launch_bounds__(256) void out_proj3(
    const unsigned short* __restrict__ att, const unsigned short* __restrict__ wob,
    const float* __restrict__ bo, float* __restrict__ out)
{
  __shared__ __attribute__((aligned(16))) unsigned short As[64][72];
  __shared__ __attribute__((aligned(16))) unsigned short Bs[128][72];

  const int nb = blockIdx.x, mbk = blockIdx.y;
  const int tid = threadIdx.x;
  const int w = tid >> 6, lane = tid & 63, c = lane & 15, quad = lane >> 4;
  const int wm = w & 1, wn = w >> 1;
  const int m0 = mbk * 64, n0 = nb * 128;
  const int arow = tid >> 2, acol = (tid & 3) * 16;
  const int brow = tid >> 1, bcol = (tid & 1) * 32;

  const unsigned short* sa = att + (size_t)(m0 + arow) * 1024 + acol;
  const unsigned short* sb = wob + (size_t)(n0 + brow) * 1024 + bcol;

  f32x4 acc[2][4] = {};

  // prologue: prefetch k0=0 tiles into registers
  u16x8 ra0 = *(const u16x8*)(sa);
  u16x8 ra1 = *(const u16x8*)(sa + 8);
  u16x8 rb0 = *(const u16x8*)(sb);
  u16x8 rb1 = *(const u16x8*)(sb + 8);
  u16x8 rb2 = *(const u16x8*)(sb + 16);
  u16x8 rb3 = *(const u16x8*)(sb + 24);

  for (int k0 = 0; k0 < 1024; k0 += 64) {
    __syncthreads();   // previous iter's LDS reads complete
    *(u16x8*)&As[arow][acol]          = ra0;
    *(u16x8*)&As[arow][acol + 8]      = ra1;
    *(u16x8*)&Bs[brow][bcol]          = rb0;
    *(u16x8*)&Bs[brow][bcol + 8]      = rb1;
    *(u16x8*)&Bs[brow][bcol + 16]     = rb2;
    *(u16x8*)&Bs[brow][bcol + 24]     = rb3;
    if (k0 < 960) {    // prefetch next K-tile; latency hidden behind MFMAs
      const unsigned short* pa = sa + k0 + 64;
      const unsigned short* pb = sb + k0 + 64;
      ra0 = *(const u16x8*)(pa);
      ra1 = *(const u16x8*)(pa + 8);
      rb0 = *(const u16x8*)(pb);
      rb1 = *(const u16x8*)(pb + 8);
      rb2 = *(const u16x8*)(pb + 16);
      rb3 = *(const u16x8*)(pb + 24);
    }
    __syncthreads();

    #pragma unroll
    for (int kk = 0; kk < 64; kk += 32) {
      bf16x8 af[2];
      #pragma unroll
      for (int mt = 0; mt < 2; ++mt)
        af[mt] = *reinterpret_cast<const bf16x8*>(&As[wm * 32 + mt * 16 + c][kk + quad * 8]);
      #pragma unroll
      for (int nt = 0; nt < 4; ++nt) {
        bf16x8 bf_ = *reinterpret_cast<const bf16x8*>(&Bs[wn * 64 + nt * 16 + c][kk + quad * 8]);
        #pragma unroll
        for (int mt = 0; mt < 2; ++mt)
          acc[mt][nt] = mfma16(af[mt], bf_, acc[mt][nt]);
      }
    }
  }

  #pragma unroll
  for (int nt = 0; nt < 4; ++nt) {
    const int col = n0 + wn * 64 + nt * 16 + c;
    const float bias = bo[col];
    #pragma unroll
    for (int mt = 0; mt < 2; ++mt)
      #pragma unroll
      for (int r = 0; r < 4; ++r)
        out[(size_t)(m0 + wm * 32 + mt * 16 + quad * 4 + r) * 1024 + col] =
            acc[mt][nt][r] + bias;
  }
}

extern "C" void kernel_launch(void* const* d_in, const int* in_sizes, int n_in,
                              void* d_out, int out_size, void* d_ws, size_t ws_size,
                              hipStream_t stream) {
  const float* keys    = (const float*)d_in[0];
  const float* values  = (const float*)d_in[1];
  const float* queries = (const float*)d_in[2];
  const int*   mask    = (const int*)d_in[3];
  const float* Wk      = (const float*)d_in[4];
  const float* Wv      = (const float*)d_in[5];
  const float* Wq      = (const float*)d_in[6];
  const float* Wo      = (const float*)d_in[7];
  const float* bo      = (const float*)d_in[8];
  float* out = (float*)d_out;

  const size_t T = (size_t)4 * NH * SEQ * HDIM;  // 8388608 elements per tensor
  unsigned short* ws  = (unsigned short*)d_ws;
  unsigned short* kb  = ws;
  unsigned short* vb  = kb + T;                  // V^T tiled [head][seq/64][d][64]
  unsigned short* qb  = vb + T;
  unsigned short* att = qb + T;
  unsigned short* wob = att + T;                 // 1024*1024 u16
  u64* mbits = (u64*)(wob + 1024 * 1024);        // 262144 u64 (2 MB)

  qkv_proj<<<dim3(512, 3), 256, 0, stream>>>(keys, values, queries,
                                             Wk, Wv, Wq, kb, vb, qb);
  cvt_wo<<<dim3(1024), 256, 0, stream>>>(Wo, wob);
  maskpack<<<dim3(4096), 256, 0, stream>>>(mask, mbits);
  attn4<<<dim3(1024), 256, 0, stream>>>(qb, kb, vb, mbits, att);
  out_proj3<<<dim3(8, 128), 256, 0, stream>>>(att, wob, bo, out);
}

// Round 15
// 339.259 us; speedup vs baseline: 1.1158x; 1.0221x over previous
//
#include <hip/hip_runtime.h>

#define SEQ 2048
#define HDIM 64
#define NH 16

typedef __bf16 bf16x8 __attribute__((ext_vector_type(8)));
typedef float f32x4 __attribute__((ext_vector_type(4)));
typedef unsigned short u16x8 __attribute__((ext_vector_type(8)));
typedef unsigned short u16x4 __attribute__((ext_vector_type(4)));
typedef _Float16 f16x4 __attribute__((ext_vector_type(4)));
typedef unsigned int u32x2 __attribute__((ext_vector_type(2)));
typedef unsigned long long u64;

__device__ __forceinline__ unsigned short f2bf(float f) {  // RTNE
  unsigned int u = __builtin_bit_cast(unsigned int, f);
  u = (u + 0x7FFFu + ((u >> 16) & 1u)) >> 16;
  return (unsigned short)u;
}

__device__ __forceinline__ bf16x8 cvt8(f32x4 a, f32x4 b) {
  u16x8 u;
  u[0] = f2bf(a[0]); u[1] = f2bf(a[1]); u[2] = f2bf(a[2]); u[3] = f2bf(a[3]);
  u[4] = f2bf(b[0]); u[5] = f2bf(b[1]); u[6] = f2bf(b[2]); u[7] = f2bf(b[3]);
  return __builtin_bit_cast(bf16x8, u);
}

__device__ __forceinline__ f32x4 mfma16(bf16x8 a, bf16x8 b, f32x4 c) {
  return __builtin_amdgcn_mfma_f32_16x16x32_bf16(a, b, c, 0, 0, 0);
}
__device__ __forceinline__ f32x4 mfma16h(f16x4 a, f16x4 b, f32x4 c) {
  return __builtin_amdgcn_mfma_f32_16x16x16f16(a, b, c, 0, 0, 0);
}

// pack 4 f32 -> f16x4 via v_cvt_pkrtz (RTZ — round-1 proven numerics)
__device__ __forceinline__ f16x4 pk4h(float a, float b, float cc, float d) {
  auto h0 = __builtin_amdgcn_cvt_pkrtz(a, b);
  auto h1 = __builtin_amdgcn_cvt_pkrtz(cc, d);
  u32x2 u = { __builtin_bit_cast(unsigned int, h0),
              __builtin_bit_cast(unsigned int, h1) };
  return __builtin_bit_cast(f16x4, u);
}

// log2(e)/32: folds 1/sqrt(EMBED_DIM) and exp->exp2 into the q-projection.
#define QSCALE 0.045084220027780106f

// ---------------- Kernel 1: QKV projection. K,Q out bf16 [m][d]; V out f16
// TILED V^T: [head][seq/64][d][64] (round-14 proven: wave-private LDS
// transpose + 8 contiguous 1KB wave-stores).
__global__ __launch_bounds__(256) void qkv_proj(
    const float* __restrict__ keys, const float* __restrict__ values,
    const float* __restrict__ queries,
    const float* __restrict__ Wk, const float* __restrict__ Wv,
    const float* __restrict__ Wq,
    unsigned short* __restrict__ kb, unsigned short* __restrict__ vb,
    unsigned short* __restrict__ qb)
{
  __shared__ __attribute__((aligned(16))) unsigned short vt[4][64][72];

  const int which = blockIdx.y;
  const float* __restrict__ in = (which == 0) ? keys : (which == 1) ? values : queries;
  const float* __restrict__ W  = (which == 0) ? Wk   : (which == 1) ? Wv     : Wq;
  unsigned short* __restrict__ op = (which == 0) ? kb : (which == 1) ? vb : qb;
  const float osc = (which == 2) ? QSCALE : 1.0f;
  const bool asf16 = (which == 1);

  const int tid = threadIdx.x;
  const int w = tid >> 6, lane = tid & 63, c = lane & 15, quad = lane >> 4;

  // A-frags of W: lane holds W[dt*16 + c][hh*32 + quad*8 ..+7]
  bf16x8 aw[4][2];
  #pragma unroll
  for (int dt = 0; dt < 4; ++dt)
    #pragma unroll
    for (int hh = 0; hh < 2; ++hh) {
      const float* wr = W + (dt * 16 + c) * 64 + hh * 32 + quad * 8;
      aw[dt][hh] = cvt8(*(const f32x4*)wr, *(const f32x4*)(wr + 4));
    }

  const int m00 = blockIdx.x * 256 + w * 64;
  #pragma unroll
  for (int s = 0; s < 4; ++s) {
    const int m0 = m00 + s * 16;
    const float* xr = in + (size_t)(m0 + c) * 64;
    bf16x8 x0 = cvt8(*(const f32x4*)(xr + quad * 8), *(const f32x4*)(xr + quad * 8 + 4));
    bf16x8 x1 = cvt8(*(const f32x4*)(xr + 32 + quad * 8), *(const f32x4*)(xr + 36 + quad * 8));
    f32x4 acc[4] = {};
    #pragma unroll
    for (int dt = 0; dt < 4; ++dt) {
      acc[dt] = mfma16(aw[dt][0], x0, acc[dt]);
      acc[dt] = mfma16(aw[dt][1], x1, acc[dt]);
    }
    if (asf16) {
      // stage into per-wave LDS transpose tile [d][seq_local]
      #pragma unroll
      for (int dt = 0; dt < 4; ++dt) {
        u16x4 pk = __builtin_bit_cast(u16x4,
            pk4h(acc[dt][0], acc[dt][1], acc[dt][2], acc[dt][3]));
        #pragma unroll
        for (int r = 0; r < 4; ++r)
          vt[w][dt * 16 + quad * 4 + r][s * 16 + c] = pk[r];
      }
    } else {
      // D[d = dt*16 + quad*4 + r][m = c] -> 4 consecutive d per lane: u16x4
      unsigned short* orow = op + (size_t)(m0 + c) * 64 + quad * 4;
      #pragma unroll
      for (int dt = 0; dt < 4; ++dt) {
        u16x4 pk;
        pk[0] = f2bf(acc[dt][0] * osc); pk[1] = f2bf(acc[dt][1] * osc);
        pk[2] = f2bf(acc[dt][2] * osc); pk[3] = f2bf(acc[dt][3] * osc);
        *(u16x4*)(orow + dt * 16) = pk;
      }
    }
  }

  if (asf16) {
    // flush the wave's 64x64 tile: 8 instrs x contiguous 1KB wave-stores.
    unsigned short* tb = op + (size_t)(m00 >> 11) * (64 * SEQ)
                            + (size_t)((m00 & 2047) >> 6) * (64 * 64);
    #pragma unroll
    for (int k = 0; k < 8; ++k) {
      const int row = k * 8 + (lane >> 3), colb = (lane & 7) * 8;
      u16x8 v = *(const u16x8*)&vt[w][row][colb];
      *(u16x8*)(tb + (size_t)row * 64 + colb) = v;
    }
  }
}

// ---------------- Kernel 2: Wo fp32 -> bf16 (one-time 4MB; keeps out_proj
// B-panel re-reads at bf16 width — in-proj fusion regressed in round 10).
__global__ __launch_bounds__(256) void cvt_wo(const float* __restrict__ src,
                                              unsigned short* __restrict__ dst)
{
  int i = (blockIdx.x * 256 + threadIdx.x) * 4;
  f32x4 v = *reinterpret_cast<const f32x4*>(src + i);
  u16x4 o;
  o[0] = f2bf(v[0]); o[1] = f2bf(v[1]); o[2] = f2bf(v[2]); o[3] = f2bf(v[3]);
  *reinterpret_cast<u16x4*>(dst + i) = o;
}

// ---------------- Kernel 3: pack mask int32 -> bitmask (67MB -> 2MB) ------
__global__ __launch_bounds__(256) void maskpack(const int* __restrict__ mask,
                                                u64* __restrict__ bits)
{
  const int wid = blockIdx.x * 4 + (threadIdx.x >> 6);
  const int lane = threadIdx.x & 63;
  const int* src = mask + (size_t)wid * 1024 + lane;
  u64* dst = bits + (size_t)wid * 16;
  #pragma unroll
  for (int i = 0; i < 16; ++i) {
    u64 b = __ballot(src[i * 64] != 0);
    if (lane == 0) dst[i] = b;
  }
}

// ---------------- Kernel 4: attention (round-14 measured best ~114.5us).
__global__ __launch_bounds__(256, 4) void attn4(
    const unsigned short* __restrict__ qb, const unsigned short* __restrict__ kb,
    const unsigned short* __restrict__ vb, const u64* __restrict__ mbits,
    unsigned short* __restrict__ att)
{
  __shared__ __attribute__((aligned(16))) unsigned short Kl[64][72]; // bf16 [key][d]
  __shared__ __attribute__((aligned(16))) unsigned short Vt[64][72]; // f16  [d][key]
  __shared__ unsigned int mlut[16][2];

  const int tid = threadIdx.x;
  const int w = tid >> 6, lane = tid & 63, c = lane & 15, quad = lane >> 4;

  // bid = (G&7) + 8*(qx + 16*(G>>3)): bid%8 == G%8 -> same head-group, same XCD
  const int bid = blockIdx.x;
  const int xcd = bid & 7, rr = bid >> 3;
  const int qx = rr & 15, gh = rr >> 4;
  const int G = xcd + gh * 8;            // head-group = n*NH + h, 0..63
  const int n = G >> 4;
  const int q0 = qx * 128;
  const size_t hb = (size_t)G * (SEQ * HDIM);

  if (tid < 16) {
    unsigned m = tid;
    mlut[m][0] = ((m & 1u) ? 0xFFFFu : 0u) | ((m & 2u) ? 0xFFFF0000u : 0u);
    mlut[m][1] = ((m & 4u) ? 0xFFFFu : 0u) | ((m & 8u) ? 0xFFFF0000u : 0u);
  }

  bf16x8 aq[2][2];
  #pragma unroll
  for (int qt = 0; qt < 2; ++qt) {
    const unsigned short* qr = qb + hb + (size_t)(q0 + qt * 64 + w * 16 + c) * HDIM;
    aq[qt][0] = *reinterpret_cast<const bf16x8*>(qr + quad * 8);
    aq[qt][1] = *reinterpret_cast<const bf16x8*>(qr + 32 + quad * 8);
  }

  f32x4 o[2][4] = {};    // O^T: lane q=qbase+c; d = dt*16 + quad*4 + r
  f32x4 osum[2] = {};    // MFMA-accumulated row sums (all entries identical)
  const f16x4 ones = {(_Float16)1.f, (_Float16)1.f, (_Float16)1.f, (_Float16)1.f};

  const u64* mb = mbits + ((size_t)n * SEQ + q0 + w * 16 + c) * 32;

  // Staging: waves 0-1 copy K rows [key][d]; waves 2-3 copy V^T tile rows.
  // Unified addressing: row srow of a 64x64-u16 tile, tiles 4096 apart.
  const bool isK = tid < 128;
  const int srow = (tid & 127) >> 1, scol = (tid & 1) * 32;
  const unsigned short* sptr = (isK ? kb : vb) + hb + (size_t)srow * 64 + scol;
  unsigned short (*Sl)[72] = isK ? Kl : Vt;

  // prologue: prefetch tile 0 + mask words 0 into registers
  u16x8 st0 = *(const u16x8*)(sptr);
  u16x8 st1 = *(const u16x8*)(sptr + 8);
  u16x8 st2 = *(const u16x8*)(sptr + 16);
  u16x8 st3 = *(const u16x8*)(sptr + 24);
  u64 mcur0 = mb[0];
  u64 mcur1 = mb[2048];

  for (int step = 0; step < 32; ++step) {
    __syncthreads();   // previous step's LDS reads complete
    *(u16x8*)&Sl[srow][scol]      = st0;
    *(u16x8*)&Sl[srow][scol + 8]  = st1;
    *(u16x8*)&Sl[srow][scol + 16] = st2;
    *(u16x8*)&Sl[srow][scol + 24] = st3;
    u64 b0 = mcur0 >> (quad * 4);
    u64 b1 = mcur1 >> (quad * 4);
    if (step < 31) {   // prefetch next tile + next mask words
      const unsigned short* p = sptr + (size_t)(step + 1) * 4096;
      st0 = *(const u16x8*)(p);
      st1 = *(const u16x8*)(p + 8);
      st2 = *(const u16x8*)(p + 16);
      st3 = *(const u16x8*)(p + 24);
      mcur0 = mb[step + 1];
      mcur1 = mb[2048 + step + 1];
    }
    __syncthreads();

    // E^T = K.Q^T : per key-tile t, K A-frag shared by both q-tiles
    f32x4 e[2][4] = {};
    #pragma unroll
    for (int t = 0; t < 4; ++t) {
      bf16x8 kf0 = *reinterpret_cast<const bf16x8*>(&Kl[t * 16 + c][quad * 8]);
      bf16x8 kf1 = *reinterpret_cast<const bf16x8*>(&Kl[t * 16 + c][32 + quad * 8]);
      #pragma unroll
      for (int qt = 0; qt < 2; ++qt) {
        e[qt][t] = mfma16(kf0, aq[qt][0], e[qt][t]);
        e[qt][t] = mfma16(kf1, aq[qt][1], e[qt][t]);
      }
    }

    // exp2 (raw v_exp_f32; in-range so bit-identical to ocml exp2f)
    // -> pack f16 -> AND with mask-LUT words
    f16x4 pf[2][4];
    #pragma unroll
    for (int qt = 0; qt < 2; ++qt) {
      u64 bb = qt ? b1 : b0;
      unsigned int lo = (unsigned int)bb, hi = (unsigned int)(bb >> 32);
      #pragma unroll
      for (int t = 0; t < 4; ++t) {
        unsigned int nib = (((t & 2) ? hi : lo) >> ((t & 1) * 16)) & 0xFu;
        f32x4 ev = e[qt][t];
        f16x4 pk = pk4h(__builtin_amdgcn_exp2f(ev[0]),
                        __builtin_amdgcn_exp2f(ev[1]),
                        __builtin_amdgcn_exp2f(ev[2]),
                        __builtin_amdgcn_exp2f(ev[3]));
        u32x2 pw = __builtin_bit_cast(u32x2, pk);
        pw[0] &= mlut[nib][0];
        pw[1] &= mlut[nib][1];
        pf[qt][t] = __builtin_bit_cast(f16x4, pw);
      }
    }

    // O^T += V^T.P^T ; row sums via ones-operand MFMA. setprio favors the
    // MFMA-entering wave over co-resident waves still issuing loads (T5).
    __builtin_amdgcn_s_setprio(1);
    #pragma unroll
    for (int dt = 0; dt < 4; ++dt) {
      #pragma unroll
      for (int t = 0; t < 4; ++t) {
        f16x4 vf = __builtin_bit_cast(f16x4,
            *(const u16x4*)&Vt[dt * 16 + c][t * 16 + quad * 4]);
        o[0][dt] = mfma16h(vf, pf[0][t], o[0][dt]);
        o[1][dt] = mfma16h(vf, pf[1][t], o[1][dt]);
      }
    }
    #pragma unroll
    for (int t = 0; t < 4; ++t) {
      osum[0] = mfma16h(ones, pf[0][t], osum[0]);
      osum[1] = mfma16h(ones, pf[1][t], osum[1]);
    }
    __builtin_amdgcn_s_setprio(0);
  }

  #pragma unroll
  for (int qt = 0; qt < 2; ++qt) {
    float inv = 1.0f / osum[qt][0];   // all 4 entries / all quads identical
    unsigned short* orow =
        att + hb + (size_t)(q0 + qt * 64 + w * 16 + c) * HDIM + quad * 4;
    #pragma unroll
    for (int dt = 0; dt < 4; ++dt) {
      u16x4 pk = { f2bf(o[qt][dt][0] * inv), f2bf(o[qt][dt][1] * inv),
                   f2bf(o[qt][dt][2] * inv), f2bf(o[qt][dt][3] * inv) };
      *(u16x4*)(orow + dt * 16) = pk;
    }
  }
}

// ---------------- Kernel 5: output projection, 128x128 tiles (512 blocks,
// acc[4][4]/wave, BK=64). The old 64x128 tile ran at ~140 TF — per-phase
// work too small to amortize barrier+latency (tile-ladder: 64²->128² was
// 343->912 TF). Bijective XCD swizzle: blocks with mbk≡xcd share an XCD ->
// 8 A-panels (2MB) + wob (2MB) L2-resident per XCD. Fragment sequence per
// output element identical to round-14 kernel -> bit-identical numerics.
__global__ __launch_bounds__(256) void out_proj4(
    const unsigned short* __restrict__ att, const unsigned short* __restrict__ wob,
    const float* __restrict__ bo, float* __restrict__ out)
{
  __shared__ __attribute__((aligned(16))) unsigned short As[128][72];
  __shared__ __attribute__((aligned(16))) unsigned short Bs[128][72];

  const int bid = blockIdx.x;            // 512 blocks
  const int xcd = bid & 7, rr = bid >> 3;
  const int nb = rr & 7, g = rr >> 3;    // g in [0,8)
  const int mbk = xcd + g * 8;           // [0,64), mbk%8 == xcd
  const int tid = threadIdx.x;
  const int w = tid >> 6, lane = tid & 63, c = lane & 15, quad = lane >> 4;
  const int wm = w & 1, wn = w >> 1;
  const int m0 = mbk * 128, n0 = nb * 128;
  const int srow = tid >> 1, scol = (tid & 1) * 32;

  const unsigned short* sa = att + (size_t)(m0 + srow) * 1024 + scol;
  const unsigned short* sb = wob + (size_t)(n0 + srow) * 1024 + scol;

  f32x4 acc[4][4] = {};

  // prologue: prefetch k0=0 tiles into registers
  u16x8 ra0 = *(const u16x8*)(sa);
  u16x8 ra1 = *(const u16x8*)(sa + 8);
  u16x8 ra2 = *(const u16x8*)(sa + 16);
  u16x8 ra3 = *(const u16x8*)(sa + 24);
  u16x8 rb0 = *(const u16x8*)(sb);
  u16x8 rb1 = *(const u16x8*)(sb + 8);
  u16x8 rb2 = *(const u16x8*)(sb + 16);
  u16x8 rb3 = *(const u16x8*)(sb + 24);

  for (int k0 = 0; k0 < 1024; k0 += 64) {
    __syncthreads();   // previous iter's LDS reads complete
    *(u16x8*)&As[srow][scol]      = ra0;
    *(u16x8*)&As[srow][scol + 8]  = ra1;
    *(u16x8*)&As[srow][scol + 16] = ra2;
    *(u16x8*)&As[srow][scol + 24] = ra3;
    *(u16x8*)&Bs[srow][scol]      = rb0;
    *(u16x8*)&Bs[srow][scol + 8]  = rb1;
    *(u16x8*)&Bs[srow][scol + 16] = rb2;
    *(u16x8*)&Bs[srow][scol + 24] = rb3;
    if (k0 < 960) {    // prefetch next K-tile; latency hidden behind MFMAs
      const unsigned short* pa = sa + k0 + 64;
      const unsigned short* pb = sb + k0 + 64;
      ra0 = *(const u16x8*)(pa);      ra1 = *(const u16x8*)(pa + 8);
      ra2 = *(const u16x8*)(pa + 16); ra3 = *(const u16x8*)(pa + 24);
      rb0 = *(const u16x8*)(pb);      rb1 = *(const u16x8*)(pb + 8);
      rb2 = *(const u16x8*)(pb + 16); rb3 = *(const u16x8*)(pb + 24);
    }
    __syncthreads();

    #pragma unroll
    for (int kk = 0; kk < 64; kk += 32) {
      bf16x8 af[4], bfr[4];
      #pragma unroll
      for (int mt = 0; mt < 4; ++mt)
        af[mt] = *reinterpret_cast<const bf16x8*>(&As[wm * 64 + mt * 16 + c][kk + quad * 8]);
      #pragma unroll
      for (int nt = 0; nt < 4; ++nt)
        bfr[nt] = *reinterpret_cast<const bf16x8*>(&Bs[wn * 64 + nt * 16 + c][kk + quad * 8]);
      #pragma unroll
      for (int nt = 0; nt < 4; ++nt)
        #pragma unroll
        for (int mt = 0; mt < 4; ++mt)
          acc[mt][nt] = mfma16(af[mt], bfr[nt], acc[mt][nt]);
    }
  }

  #pragma unroll
  for (int nt = 0; nt < 4; ++nt) {
    const int col = n0 + wn * 64 + nt * 16 + c;
    const float bias = bo[col];
    #pragma unroll
    for (int mt = 0; mt < 4; ++mt)
      #pragma unroll
      for (int r = 0; r < 4; ++r)
        out[(size_t)(m0 + wm * 64 + mt * 16 + quad * 4 + r) * 1024 + col] =
            acc[mt][nt][r] + bias;
  }
}

extern "C" void kernel_launch(void* const* d_in, const int* in_sizes, int n_in,
                              void* d_out, int out_size, void* d_ws, size_t ws_size,
                              hipStream_t stream) {
  const float* keys    = (const float*)d_in[0];
  const float* values  = (const float*)d_in[1];
  const float* queries = (const float*)d_in[2];
  const int*   mask    = (const int*)d_in[3];
  const float* Wk      = (const float*)d_in[4];
  const float* Wv      = (const float*)d_in[5];
  const float* Wq      = (const float*)d_in[6];
  const float* Wo      = (const float*)d_in[7];
  const float* bo      = (const float*)d_in[8];
  float* out = (float*)d_out;

  const size_t T = (size_t)4 * NH * SEQ * HDIM;  // 8388608 elements per tensor
  unsigned short* ws  = (unsigned short*)d_ws;
  unsigned short* kb  = ws;
  unsigned short* vb  = kb + T;                  // V^T tiled [head][seq/64][d][64]
  unsigned short* qb  = vb + T;
  unsigned short* att = qb + T;
  unsigned short* wob = att + T;                 // 1024*1024 u16
  u64* mbits = (u64*)(wob + 1024 * 1024);        // 262144 u64 (2 MB)

  qkv_proj<<<dim3(512, 3), 256, 0, stream>>>(keys, values, queries,
                                             Wk, Wv, Wq, kb, vb, qb);
  cvt_wo<<<dim3(1024), 256, 0, stream>>>(Wo, wob);
  maskpack<<<dim3(4096), 256, 0, stream>>>(mask, mbits);
  attn4<<<dim3(1024), 256, 0, stream>>>(qb, kb, vb, mbits, att);
  out_proj4<<<dim3(512), 256, 0, stream>>>(att, wob, bo, out);
}